// Round 1
// baseline (126.923 us; speedup 1.0000x reference)
//
#include <hip/hip_runtime.h>

#define NBINS 101
#define NB2 (2 * NBINS)    // 202 bins total (pos + neg)
#define NTHREADS 256
#define NCOPY 32           // histogram replicas, one per lane&31 (bank = copy)
#define CNT_SHIFT 22
#define QMAX 413695u       // (100<<12) | 4095 : clamps idx to <= 100
#define FSCALE 452.5483399593904f   // sqrt(50 * 4096): folds (s+1)*204800 into MFMA

typedef _Float16 half8 __attribute__((ext_vector_type(8)));
typedef float floatx4 __attribute__((ext_vector_type(4)));

// ---------------------------------------------------------------------------
// R10: dispatch-structure round. hist_pairs core (MFMA q-space binning, packed
// LDS atomics) is untouched — it is arithmetically a ~5-10us kernel. The
// single-block reduce_finalize kernel (waits on all 520 blocks, 840KB partials
// L2 round-trip at one CU's BW, serial fp64 tail, plus a graph-node gap) is
// deleted: each block atomicAdds integer per-bin sums (count u32, frac-q12
// u64) to global accumulators — order-independent => bit-deterministic — and
// the last block (threadfence + ticket) telescopes + finalizes inline.
// convert_kernel (stream-ordered before hist) zeros the 2.5KB accumulators.
// ---------------------------------------------------------------------------

__global__ __launch_bounds__(NTHREADS)
void convert_kernel(const float* __restrict__ feats,
                    const int* __restrict__ classes,
                    _Float16* __restrict__ wsF,
                    unsigned char* __restrict__ wsC,
                    unsigned long long* __restrict__ gF,  // [NB2] frac sums (q12)
                    unsigned* __restrict__ gC,            // [NB2] counts
                    unsigned* __restrict__ ticket,
                    int ngroups,   // N*D/8 groups of 8 floats
                    int n) {       // N (classes)
    int t = blockIdx.x * NTHREADS + threadIdx.x;
    if (t < ngroups) {
        const float4* p = (const float4*)feats + (size_t)t * 2;
        float4 f0 = p[0];
        float4 f1 = p[1];
        half8 h;
        h[0] = (_Float16)(f0.x * FSCALE); h[1] = (_Float16)(f0.y * FSCALE);
        h[2] = (_Float16)(f0.z * FSCALE); h[3] = (_Float16)(f0.w * FSCALE);
        h[4] = (_Float16)(f1.x * FSCALE); h[5] = (_Float16)(f1.y * FSCALE);
        h[6] = (_Float16)(f1.z * FSCALE); h[7] = (_Float16)(f1.w * FSCALE);
        *(half8*)(wsF + (size_t)t * 8) = h;
    }
    if (t < n) wsC[t] = (unsigned char)classes[t];
    // zero the global accumulators (workspace is poisoned each iteration);
    // stream order guarantees this completes before hist_pairs launches.
    if (blockIdx.x == 0) {
        int z = threadIdx.x;
        if (z < NB2) { gF[z] = 0ull; gC[z] = 0u; }
        if (z == NB2) *ticket = 0u;
    }
}

// ---------------------------------------------------------------------------
// One 64x64 upper-triangular tile per wave; half8 fragment loads from the
// scaled f16 workspace; acc arrives in q-space (bias pre-added); one
// ds_add_u32 per pair; per-block unpack -> 2 global integer atomics per bin;
// last block telescopes + fp64-finalizes inline.
// ---------------------------------------------------------------------------
__global__ __launch_bounds__(NTHREADS, 4)
void hist_pairs_kernel(const _Float16* __restrict__ feats16,
                       const unsigned char* __restrict__ cls8,
                       unsigned long long* __restrict__ gF,
                       unsigned* __restrict__ gC,
                       unsigned* __restrict__ ticket,
                       float* __restrict__ out,
                       int ntiles, int njobs) {
    __shared__ unsigned lhist[NB2][NCOPY];   // packed count|frac, 25.9 KB
    __shared__ __align__(16) int cls[4][2][64];  // [wave][A/B][row]
    __shared__ double hd[NB2];               // finalize scratch (last block)
    __shared__ int lastflag;

    const int tid = threadIdx.x;
    const int wave = tid >> 6;
    const int lane = tid & 63;

    // zero local histograms (uint4 stores: 1616 x 16B / 256 thr)
    {
        uint4* z = (uint4*)&lhist[0][0];
        uint4 zero = {0u, 0u, 0u, 0u};
        for (int t = tid; t < NB2 * NCOPY / 4; t += NTHREADS) z[t] = zero;
    }

    // one 64x64 upper-triangular tile per wave
    const int job = blockIdx.x * 4 + wave;
    int ti = 0, tj = 0;
    if (job < njobs) {
        int rem = job;
        while (rem >= ntiles - ti) { rem -= ntiles - ti; ++ti; }
        tj = ti + rem;
        cls[wave][0][lane] = cls8[ti * 64 + lane];
        cls[wave][1][lane] = cls8[tj * 64 + lane];
    }
    __syncthreads();

    if (job < njobs) {
        const int i0 = ti * 64, j0 = tj * 64;
        const int lr = lane & 15;
        const int quad = lane >> 4;

        const _Float16* Ab = feats16 + (size_t)(i0 + lr) * 128 + quad * 8;
        const _Float16* Bb = feats16 + (size_t)(j0 + lr) * 128 + quad * 8;

        // acc initialized to the binning bias: (s+1)*204800 + 0.5 rounding
        floatx4 acc[4][4];
        #pragma unroll
        for (int mi = 0; mi < 4; ++mi)
            #pragma unroll
            for (int ni = 0; ni < 4; ++ni) {
                acc[mi][ni][0] = 204800.5f; acc[mi][ni][1] = 204800.5f;
                acc[mi][ni][2] = 204800.5f; acc[mi][ni][3] = 204800.5f;
            }

        #pragma unroll
        for (int ks = 0; ks < 128; ks += 32) {
            half8 af[4], bf[4];
            #pragma unroll
            for (int mi = 0; mi < 4; ++mi)
                af[mi] = *(const half8*)(Ab + (size_t)mi * 16 * 128 + ks);
            #pragma unroll
            for (int ni = 0; ni < 4; ++ni)
                bf[ni] = *(const half8*)(Bb + (size_t)ni * 16 * 128 + ks);
            #pragma unroll
            for (int mi = 0; mi < 4; ++mi)
                #pragma unroll
                for (int ni = 0; ni < 4; ++ni)
                    acc[mi][ni] = __builtin_amdgcn_mfma_f32_16x16x32_f16(
                        af[mi], bf[ni], acc[mi][ni], 0, 0, 0);
        }

        // classes for this lane's C fragment rows/cols
        int cA[4][4], cB[4];
        #pragma unroll
        for (int mi = 0; mi < 4; ++mi) {
            int4 c4 = *(const int4*)&cls[wave][0][mi * 16 + quad * 4];
            cA[mi][0] = c4.x; cA[mi][1] = c4.y;
            cA[mi][2] = c4.z; cA[mi][3] = c4.w;
        }
        #pragma unroll
        for (int ni = 0; ni < 4; ++ni) cB[ni] = cls[wave][1][ni * 16 + lr];

        // binning: acc already equals q + tiny fp noise. One ds_add_u32/pair.
        const int copy = lane & (NCOPY - 1);
        unsigned* hb = &lhist[0][0] + copy;
        const bool diag = (ti == tj);
        #pragma unroll
        for (int mi = 0; mi < 4; ++mi) {
            #pragma unroll
            for (int ni = 0; ni < 4; ++ni) {
                #pragma unroll
                for (int r = 0; r < 4; ++r) {
                    const int li = mi * 16 + quad * 4 + r;
                    const int lj = ni * 16 + lr;
                    if (diag && li >= lj) continue;  // strict upper triangle
                    float qf = fmaxf(acc[mi][ni][r], 0.0f);
                    unsigned q = (unsigned)qf;
                    q = q > QMAX ? QMAX : q;
                    unsigned idx = q >> 12;
                    unsigned word = (q & 4095u) | (1u << CNT_SHIFT);
                    unsigned hoff = (cA[mi][r] == cB[ni]) ? 0u : (unsigned)NBINS;
                    atomicAdd(hb + (hoff + idx) * NCOPY, word);
                }
            }
        }
    }
    __syncthreads();

    // per-bin unpack: C = sum(w>>22), Fq = sum(w&mask) (q12 fixed point).
    // Telescope is linear, so it moves to the finalize after global summation.
    const int t = tid;
    if (t < NB2) {
        unsigned Cs = 0, Fq = 0;
        #pragma unroll
        for (int c = 0; c < NCOPY; ++c) {
            unsigned w = lhist[t][(c + t) & (NCOPY - 1)];
            Cs += w >> CNT_SHIFT;
            Fq += w & ((1u << CNT_SHIFT) - 1);   // <= 32*2^21 = 2^26, safe
        }
        atomicAdd(&gC[t], Cs);                         // device-scope (G12)
        atomicAdd(&gF[t], (unsigned long long)Fq);     // total <= ~3.5e10, u64
    }
    __threadfence();
    __syncthreads();

    // last-block-done: ticket after all this block's atomics are ordered
    if (tid == 0) {
        unsigned old = __hip_atomic_fetch_add(ticket, 1u, __ATOMIC_ACQ_REL,
                                              __HIP_MEMORY_SCOPE_AGENT);
        lastflag = (old == (unsigned)(gridDim.x - 1));
    }
    __syncthreads();
    if (!lastflag) return;
    __threadfence();

    // ---- finalize (runs once, on the last block to arrive) ----
    // h[t] = C[t] - (t<hi)F[t]/4096 + (t>lo)F[t-1]/4096 per 101-bin segment
    if (t < NB2) {
        unsigned Ct = __hip_atomic_load(&gC[t], __ATOMIC_RELAXED,
                                        __HIP_MEMORY_SCOPE_AGENT);
        unsigned long long Ft = __hip_atomic_load(&gF[t], __ATOMIC_RELAXED,
                                                  __HIP_MEMORY_SCOPE_AGENT);
        unsigned long long Fp = 0ull;
        if (t > 0)
            Fp = __hip_atomic_load(&gF[t - 1], __ATOMIC_RELAXED,
                                   __HIP_MEMORY_SCOPE_AGENT);
        const int lo = (t < NBINS) ? 0 : NBINS;
        const int hi = lo + NBINS - 1;
        double h = (double)Ct;
        if (t < hi) h -= (double)Ft * (1.0 / 4096.0);
        if (t > lo) h += (double)Fp * (1.0 / 4096.0);
        hd[t] = h;
    }
    __syncthreads();
    if (tid == 0) {
        double sp = 0.0, sn = 0.0;
        for (int k = 0; k < NBINS; ++k) { sp += hd[k]; sn += hd[NBINS + k]; }
        double isp = 1.0 / sp, isn = 1.0 / sn;
        double cdf = 0.0, res = 0.0;
        for (int k = 0; k < NBINS; ++k) {
            cdf += hd[k] * isp;                       // inclusive cumsum of pos
            res += hd[NBINS + k] * isn * cdf;         // dot with neg
        }
        out[0] = (float)res;
    }
}

extern "C" void kernel_launch(void* const* d_in, const int* in_sizes, int n_in,
                              void* d_out, int out_size, void* d_ws, size_t ws_size,
                              hipStream_t stream) {
    const float* feats   = (const float*)d_in[0];
    const int*   classes = (const int*)d_in[1];
    float* out = (float*)d_out;

    int N = in_sizes[1];                       // 4096
    int D = in_sizes[0] / N;                   // 128
    int ntiles = N / 64;                       // 64
    int njobs = ntiles * (ntiles + 1) / 2;     // 2080 wave-jobs
    int nblocks = (njobs + 3) / 4;             // 520 blocks, 4 jobs each

    // workspace layout: f16 scaled feats | u8 classes | u64 gF | u32 gC | ticket
    _Float16* wsF = (_Float16*)d_ws;
    unsigned char* wsC = (unsigned char*)(wsF + (size_t)N * D);
    unsigned long long* gF = (unsigned long long*)(wsC + ((N + 15) & ~15));
    unsigned* gC = (unsigned*)(gF + NB2);
    unsigned* ticket = gC + NB2;

    int ngroups = N * D / 8;                   // 65536 groups of 8 floats
    int cblocks = (ngroups + NTHREADS - 1) / NTHREADS;
    convert_kernel<<<cblocks, NTHREADS, 0, stream>>>(feats, classes, wsF, wsC,
                                                     gF, gC, ticket, ngroups, N);
    hist_pairs_kernel<<<nblocks, NTHREADS, 0, stream>>>(wsF, wsC, gF, gC, ticket,
                                                        out, ntiles, njobs);
}

// Round 2
// 118.430 us; speedup vs baseline: 1.0717x; 1.0717x over previous
//
#include <hip/hip_runtime.h>

#define NBINS 101
#define NB2 (2 * NBINS)    // 202 bins total (pos + neg)
#define NTHREADS 256
#define NCOPY 32           // histogram replicas, one per lane&31 (bank = copy)
#define CNT_SHIFT 22
#define QMAX 413695u       // (100<<12) | 4095 : clamps idx to <= 100
#define FSCALE 452.5483399593904f   // sqrt(50 * 4096): folds (s+1)*204800 into MFMA

typedef _Float16 half8 __attribute__((ext_vector_type(8)));
typedef float floatx4 __attribute__((ext_vector_type(4)));

// ---------------------------------------------------------------------------
// R11: occupancy round + tail revert.
// R10 post-mortem: per-block __threadfence + ACQ_REL ticket invalidated the
// XCD L2 520 times during the kernel -> refetch storm (FETCH 4.2MB = 4x
// feats16, latency-bound at ~55 GB/s) -> hist 76us. Fences removed; tail
// reverted to R9's contention-free f32 partials + separate reduce kernel.
// Core fix: R9/R10 ran only 2080 waves = 2 waves/SIMD (Occupancy 12%) --
// unhidden L2/L3 latency. Now: 64x64 tile per BLOCK (4 waves x 16x64 strips
// sharing one LDS histogram) -> 2080 blocks, 5 blocks/CU by LDS, ~20
// waves/CU. Same MFMA q-space binning math, verified absmax 0.0 path.
// ---------------------------------------------------------------------------

__global__ __launch_bounds__(NTHREADS)
void convert_kernel(const float* __restrict__ feats,
                    const int* __restrict__ classes,
                    _Float16* __restrict__ wsF,
                    unsigned char* __restrict__ wsC,
                    int ngroups,   // N*D/8 groups of 8 floats
                    int n) {       // N (classes)
    int t = blockIdx.x * NTHREADS + threadIdx.x;
    if (t < ngroups) {
        const float4* p = (const float4*)feats + (size_t)t * 2;
        float4 f0 = p[0];
        float4 f1 = p[1];
        half8 h;
        h[0] = (_Float16)(f0.x * FSCALE); h[1] = (_Float16)(f0.y * FSCALE);
        h[2] = (_Float16)(f0.z * FSCALE); h[3] = (_Float16)(f0.w * FSCALE);
        h[4] = (_Float16)(f1.x * FSCALE); h[5] = (_Float16)(f1.y * FSCALE);
        h[6] = (_Float16)(f1.z * FSCALE); h[7] = (_Float16)(f1.w * FSCALE);
        *(half8*)(wsF + (size_t)t * 8) = h;
    }
    if (t < n) wsC[t] = (unsigned char)classes[t];
}

// ---------------------------------------------------------------------------
// One 64x64 upper-triangular tile per BLOCK; wave w computes the 16x64 strip
// rows [w*16, w*16+16). half8 fragment loads from the scaled f16 workspace;
// acc arrives in q-space (bias pre-added); one ds_add_u32 per pair;
// per-block unpack + telescope -> f32 partials row (contention-free).
// ---------------------------------------------------------------------------
__global__ __launch_bounds__(NTHREADS, 4)
void hist_pairs_kernel(const _Float16* __restrict__ feats16,
                       const unsigned char* __restrict__ cls8,
                       float* __restrict__ partials,  // [nblocks][NB2]
                       int ntiles) {
    __shared__ unsigned lhist[NB2][NCOPY];   // packed count|frac, 25.9 KB
    __shared__ float Fbuf[NB2];
    __shared__ __align__(16) int cls[2][64]; // [A/B][row], shared by all waves

    const int tid = threadIdx.x;
    const int wave = tid >> 6;
    const int lane = tid & 63;

    // zero local histograms (uint4 stores: 1616 x 16B / 256 thr)
    {
        uint4* z = (uint4*)&lhist[0][0];
        uint4 zero = {0u, 0u, 0u, 0u};
        for (int t = tid; t < NB2 * NCOPY / 4; t += NTHREADS) z[t] = zero;
    }

    // decode block -> upper-triangular tile (ti, tj)
    int ti = 0, tj = 0;
    {
        int rem = blockIdx.x;
        while (rem >= ntiles - ti) { rem -= ntiles - ti; ++ti; }
        tj = ti + rem;
    }
    if (tid < 64)        cls[0][tid]      = cls8[ti * 64 + tid];
    else if (tid < 128)  cls[1][tid - 64] = cls8[tj * 64 + (tid - 64)];
    __syncthreads();

    {
        const int i0 = ti * 64, j0 = tj * 64;
        const int lr = lane & 15;
        const int quad = lane >> 4;

        // wave-private A strip (16 rows), block-shared B tile (64 cols)
        const _Float16* Ab = feats16 + (size_t)(i0 + wave * 16 + lr) * 128 + quad * 8;
        const _Float16* Bb = feats16 + (size_t)(j0 + lr) * 128 + quad * 8;

        // acc initialized to the binning bias: (s+1)*204800 + 0.5 rounding
        floatx4 acc[4];
        #pragma unroll
        for (int ni = 0; ni < 4; ++ni) {
            acc[ni][0] = 204800.5f; acc[ni][1] = 204800.5f;
            acc[ni][2] = 204800.5f; acc[ni][3] = 204800.5f;
        }

        #pragma unroll
        for (int ks = 0; ks < 128; ks += 32) {
            half8 af = *(const half8*)(Ab + ks);
            half8 bf[4];
            #pragma unroll
            for (int ni = 0; ni < 4; ++ni)
                bf[ni] = *(const half8*)(Bb + (size_t)ni * 16 * 128 + ks);
            #pragma unroll
            for (int ni = 0; ni < 4; ++ni)
                acc[ni] = __builtin_amdgcn_mfma_f32_16x16x32_f16(
                    af, bf[ni], acc[ni], 0, 0, 0);
        }

        // classes for this lane's C fragment rows/cols
        int cA[4], cB[4];
        {
            int4 c4 = *(const int4*)&cls[0][wave * 16 + quad * 4];
            cA[0] = c4.x; cA[1] = c4.y; cA[2] = c4.z; cA[3] = c4.w;
        }
        #pragma unroll
        for (int ni = 0; ni < 4; ++ni) cB[ni] = cls[1][ni * 16 + lr];

        // binning: acc already equals q + tiny fp noise. One ds_add_u32/pair.
        const int copy = lane & (NCOPY - 1);
        unsigned* hb = &lhist[0][0] + copy;
        const bool diag = (ti == tj);
        #pragma unroll
        for (int ni = 0; ni < 4; ++ni) {
            #pragma unroll
            for (int r = 0; r < 4; ++r) {
                const int li = wave * 16 + quad * 4 + r;
                const int lj = ni * 16 + lr;
                if (diag && li >= lj) continue;  // strict upper triangle
                float qf = fmaxf(acc[ni][r], 0.0f);
                unsigned q = (unsigned)qf;
                q = q > QMAX ? QMAX : q;
                unsigned idx = q >> 12;
                unsigned word = (q & 4095u) | (1u << CNT_SHIFT);
                unsigned hoff = (cA[r] == cB[ni]) ? 0u : (unsigned)NBINS;
                atomicAdd(hb + (hoff + idx) * NCOPY, word);
            }
        }
    }
    __syncthreads();

    // per-bin unpack: C = sum(w>>22), F = sum(w&mask)/4096, then telescope:
    // h[t] = C[t] - (t<hi)F[t] + (t>lo)F[t-1]  per 101-bin segment.
    // Max adds per (bin,copy) = 2 lanes * 16 pairs = 32 -> packed fields safe.
    const int t = tid;
    float myC = 0.0f, myF = 0.0f;
    if (t < NB2) {
        unsigned Cs = 0, Fq = 0;
        #pragma unroll
        for (int c = 0; c < NCOPY; ++c) {
            unsigned w = lhist[t][(c + t) & (NCOPY - 1)];
            Cs += w >> CNT_SHIFT;
            Fq += w & ((1u << CNT_SHIFT) - 1);
        }
        myC = (float)Cs;
        myF = (float)Fq * (1.0f / 4096.0f);
        Fbuf[t] = myF;
    }
    __syncthreads();
    if (t < NB2) {
        const int lo = (t < NBINS) ? 0 : NBINS;
        const int hi = lo + NBINS - 1;
        float h = myC;
        if (t < hi) h -= myF;
        if (t > lo) h += Fbuf[t - 1];
        partials[(size_t)blockIdx.x * NB2 + t] = h;
    }
}

// ---------------------------------------------------------------------------
// Sum partial rows (coalesced, 5-way row split), then fp64 finalize:
// normalize, inclusive cumsum of pos, dot with neg.
// ---------------------------------------------------------------------------
__global__ __launch_bounds__(1024)
void reduce_finalize_kernel(const float* __restrict__ partials,
                            float* __restrict__ out, int nrows) {
    __shared__ float acc[5][NB2];
    __shared__ float h[NB2];
    const int t = threadIdx.x;
    const int g = t / NB2;          // group 0..4 (t >= 1010 idle)
    const int bin = t - g * NB2;
    if (g < 5) {
        float s = 0.0f;
        #pragma unroll 4
        for (int r = g; r < nrows; r += 5)
            s += partials[(size_t)r * NB2 + bin];
        acc[g][bin] = s;
    }
    __syncthreads();
    if (t < NB2)
        h[t] = acc[0][t] + acc[1][t] + acc[2][t] + acc[3][t] + acc[4][t];
    __syncthreads();
    if (t == 0) {
        double sp = 0.0, sn = 0.0;
        for (int k = 0; k < NBINS; ++k) { sp += h[k]; sn += h[NBINS + k]; }
        double isp = 1.0 / sp, isn = 1.0 / sn;
        double cdf = 0.0, res = 0.0;
        for (int k = 0; k < NBINS; ++k) {
            cdf += (double)h[k] * isp;                 // inclusive cumsum of pos
            res += (double)h[NBINS + k] * isn * cdf;   // dot with neg
        }
        out[0] = (float)res;
    }
}

extern "C" void kernel_launch(void* const* d_in, const int* in_sizes, int n_in,
                              void* d_out, int out_size, void* d_ws, size_t ws_size,
                              hipStream_t stream) {
    const float* feats   = (const float*)d_in[0];
    const int*   classes = (const int*)d_in[1];
    float* out = (float*)d_out;

    int N = in_sizes[1];                       // 4096
    int D = in_sizes[0] / N;                   // 128
    int ntiles = N / 64;                       // 64
    int nblocks = ntiles * (ntiles + 1) / 2;   // 2080 blocks, one tile each

    // workspace layout: f16 scaled feats | u8 classes | fp32 partials
    _Float16* wsF = (_Float16*)d_ws;
    unsigned char* wsC = (unsigned char*)(wsF + (size_t)N * D);
    float* partials = (float*)(wsC + ((N + 15) & ~15));

    int ngroups = N * D / 8;                   // 65536 groups of 8 floats
    int cblocks = (ngroups + NTHREADS - 1) / NTHREADS;
    convert_kernel<<<cblocks, NTHREADS, 0, stream>>>(feats, classes, wsF, wsC,
                                                     ngroups, N);
    hist_pairs_kernel<<<nblocks, NTHREADS, 0, stream>>>(wsF, wsC, partials,
                                                        ntiles);
    reduce_finalize_kernel<<<1, 1024, 0, stream>>>(partials, out, nblocks);
}

// Round 3
// 84.214 us; speedup vs baseline: 1.5071x; 1.4063x over previous
//
#include <hip/hip_runtime.h>

#define NBINS 101
#define NB2 (2 * NBINS)    // 202 bins total (pos + neg)
#define NTHREADS 256
#define NCOPY 32           // histogram replicas, one per lane&31 (bank = copy)
#define CNT_SHIFT 22
#define QMAX 413695u       // (100<<12) | 4095 : clamps idx to <= 100
#define GSHIFT 38          // global u64 packing: (count << 38) | frac_q12
#define NREP 8             // global accumulator replicas (one per XCD)
#define FSCALE 452.5483399593904f   // sqrt(50 * 4096): folds (s+1)*204800 into MFMA

typedef _Float16 half8 __attribute__((ext_vector_type(8)));
typedef float floatx4 __attribute__((ext_vector_type(4)));

// ---------------------------------------------------------------------------
// R12: kill the serial tail. R11 post-mortem: hist dropped 76->~22us
// (occupancy fix confirmed) but the 4x-larger partials matrix (2080x202,
// 1.68MB) fed a single-block reduce: 45us at 18.7 GB/s = one CU's stream
// rate. Fix: no partials. Each hist block packs per-bin (count,frac) into
// one u64 ((C<<38)|F; global sums fit both fields carry-free) and does ONE
// plain atomicAdd per bin into 8 XCD-spread replica rows. No threadfence,
// no ticket (R10's regression was the fence-driven L2 invalidation storm,
// not atomics). Integer adds are order-independent -> bit-deterministic.
// Finalize = one tiny 256-thread block reading 13KB.
// ---------------------------------------------------------------------------

__global__ __launch_bounds__(NTHREADS)
void convert_kernel(const float* __restrict__ feats,
                    const int* __restrict__ classes,
                    _Float16* __restrict__ wsF,
                    unsigned char* __restrict__ wsC,
                    unsigned long long* __restrict__ gH,  // [NREP][NB2]
                    int ngroups,   // N*D/8 groups of 8 floats
                    int n) {       // N (classes)
    int t = blockIdx.x * NTHREADS + threadIdx.x;
    if (t < ngroups) {
        const float4* p = (const float4*)feats + (size_t)t * 2;
        float4 f0 = p[0];
        float4 f1 = p[1];
        half8 h;
        h[0] = (_Float16)(f0.x * FSCALE); h[1] = (_Float16)(f0.y * FSCALE);
        h[2] = (_Float16)(f0.z * FSCALE); h[3] = (_Float16)(f0.w * FSCALE);
        h[4] = (_Float16)(f1.x * FSCALE); h[5] = (_Float16)(f1.y * FSCALE);
        h[6] = (_Float16)(f1.z * FSCALE); h[7] = (_Float16)(f1.w * FSCALE);
        *(half8*)(wsF + (size_t)t * 8) = h;
    }
    if (t < n) wsC[t] = (unsigned char)classes[t];
    // zero global accumulators (workspace is poisoned each iteration);
    // stream order guarantees completion before hist_pairs launches.
    if (blockIdx.x == 0) {
        for (int z = threadIdx.x; z < NREP * NB2; z += NTHREADS) gH[z] = 0ull;
    }
}

// ---------------------------------------------------------------------------
// One 64x64 upper-triangular tile per BLOCK; wave w computes the 16x64 strip
// rows [w*16, w*16+16). half8 fragment loads from the scaled f16 workspace;
// acc arrives in q-space (bias pre-added); one ds_add_u32 per pair;
// per-block unpack -> one u64 global atomicAdd per bin (XCD-spread replica).
// ---------------------------------------------------------------------------
__global__ __launch_bounds__(NTHREADS, 4)
void hist_pairs_kernel(const _Float16* __restrict__ feats16,
                       const unsigned char* __restrict__ cls8,
                       unsigned long long* __restrict__ gH,  // [NREP][NB2]
                       int ntiles) {
    __shared__ unsigned lhist[NB2][NCOPY];   // packed count|frac, 25.9 KB
    __shared__ __align__(16) int cls[2][64]; // [A/B][row], shared by all waves

    const int tid = threadIdx.x;
    const int wave = tid >> 6;
    const int lane = tid & 63;

    // zero local histograms (uint4 stores: 1616 x 16B / 256 thr)
    {
        uint4* z = (uint4*)&lhist[0][0];
        uint4 zero = {0u, 0u, 0u, 0u};
        for (int t = tid; t < NB2 * NCOPY / 4; t += NTHREADS) z[t] = zero;
    }

    // decode block -> upper-triangular tile (ti, tj)
    int ti = 0, tj = 0;
    {
        int rem = blockIdx.x;
        while (rem >= ntiles - ti) { rem -= ntiles - ti; ++ti; }
        tj = ti + rem;
    }
    if (tid < 64)        cls[0][tid]      = cls8[ti * 64 + tid];
    else if (tid < 128)  cls[1][tid - 64] = cls8[tj * 64 + (tid - 64)];
    __syncthreads();

    {
        const int i0 = ti * 64, j0 = tj * 64;
        const int lr = lane & 15;
        const int quad = lane >> 4;

        // wave-private A strip (16 rows), block-shared B tile (64 cols)
        const _Float16* Ab = feats16 + (size_t)(i0 + wave * 16 + lr) * 128 + quad * 8;
        const _Float16* Bb = feats16 + (size_t)(j0 + lr) * 128 + quad * 8;

        // acc initialized to the binning bias: (s+1)*204800 + 0.5 rounding
        floatx4 acc[4];
        #pragma unroll
        for (int ni = 0; ni < 4; ++ni) {
            acc[ni][0] = 204800.5f; acc[ni][1] = 204800.5f;
            acc[ni][2] = 204800.5f; acc[ni][3] = 204800.5f;
        }

        #pragma unroll
        for (int ks = 0; ks < 128; ks += 32) {
            half8 af = *(const half8*)(Ab + ks);
            half8 bf[4];
            #pragma unroll
            for (int ni = 0; ni < 4; ++ni)
                bf[ni] = *(const half8*)(Bb + (size_t)ni * 16 * 128 + ks);
            #pragma unroll
            for (int ni = 0; ni < 4; ++ni)
                acc[ni] = __builtin_amdgcn_mfma_f32_16x16x32_f16(
                    af, bf[ni], acc[ni], 0, 0, 0);
        }

        // classes for this lane's C fragment rows/cols
        int cA[4], cB[4];
        {
            int4 c4 = *(const int4*)&cls[0][wave * 16 + quad * 4];
            cA[0] = c4.x; cA[1] = c4.y; cA[2] = c4.z; cA[3] = c4.w;
        }
        #pragma unroll
        for (int ni = 0; ni < 4; ++ni) cB[ni] = cls[1][ni * 16 + lr];

        // binning: acc already equals q + tiny fp noise. One ds_add_u32/pair.
        const int copy = lane & (NCOPY - 1);
        unsigned* hb = &lhist[0][0] + copy;
        const bool diag = (ti == tj);
        #pragma unroll
        for (int ni = 0; ni < 4; ++ni) {
            #pragma unroll
            for (int r = 0; r < 4; ++r) {
                const int li = wave * 16 + quad * 4 + r;
                const int lj = ni * 16 + lr;
                if (diag && li >= lj) continue;  // strict upper triangle
                float qf = fmaxf(acc[ni][r], 0.0f);
                unsigned q = (unsigned)qf;
                q = q > QMAX ? QMAX : q;
                unsigned idx = q >> 12;
                unsigned word = (q & 4095u) | (1u << CNT_SHIFT);
                unsigned hoff = (cA[r] == cB[ni]) ? 0u : (unsigned)NBINS;
                atomicAdd(hb + (hoff + idx) * NCOPY, word);
            }
        }
    }
    __syncthreads();

    // per-bin unpack: C = sum(w>>22), Fq = sum(w&mask) (q12 fixed point).
    // Max adds per (bin,copy) = 2 lanes * 16 pairs = 32 -> packed fields safe.
    // Pack (C<<38)|Fq into one u64 atomicAdd; per-block Fq <= 16384*4095 <
    // 2^27 << 2^38, global F-sum <= 3.44e10 < 2^38, global C-sum < 2^26:
    // both fields sum carry-free across all 2080 blocks.
    const int t = tid;
    if (t < NB2) {
        unsigned Cs = 0, Fq = 0;
        #pragma unroll
        for (int c = 0; c < NCOPY; ++c) {
            unsigned w = lhist[t][(c + t) & (NCOPY - 1)];
            Cs += w >> CNT_SHIFT;
            Fq += w & ((1u << CNT_SHIFT) - 1);
        }
        unsigned long long word =
            ((unsigned long long)Cs << GSHIFT) | (unsigned long long)Fq;
        atomicAdd(&gH[(blockIdx.x & (NREP - 1)) * NB2 + t], word);
    }
}

// ---------------------------------------------------------------------------
// Tiny finalize: sum 8 replica rows (13KB), unpack, telescope, fp64 cumsum.
// ---------------------------------------------------------------------------
__global__ __launch_bounds__(NTHREADS)
void finalize_kernel(const unsigned long long* __restrict__ gH,
                     float* __restrict__ out) {
    __shared__ double Cd[NB2];
    __shared__ double Fd[NB2];
    __shared__ double hd[NB2];
    const int t = threadIdx.x;
    if (t < NB2) {
        unsigned long long w = 0ull;
        #pragma unroll
        for (int r = 0; r < NREP; ++r) w += gH[r * NB2 + t];
        Cd[t] = (double)(w >> GSHIFT);
        Fd[t] = (double)(w & ((1ull << GSHIFT) - 1)) * (1.0 / 4096.0);
    }
    __syncthreads();
    if (t < NB2) {
        const int lo = (t < NBINS) ? 0 : NBINS;
        const int hi = lo + NBINS - 1;
        double h = Cd[t];
        if (t < hi) h -= Fd[t];
        if (t > lo) h += Fd[t - 1];
        hd[t] = h;
    }
    __syncthreads();
    if (t == 0) {
        double sp = 0.0, sn = 0.0;
        for (int k = 0; k < NBINS; ++k) { sp += hd[k]; sn += hd[NBINS + k]; }
        double isp = 1.0 / sp, isn = 1.0 / sn;
        double cdf = 0.0, res = 0.0;
        for (int k = 0; k < NBINS; ++k) {
            cdf += hd[k] * isp;                   // inclusive cumsum of pos
            res += hd[NBINS + k] * isn * cdf;     // dot with neg
        }
        out[0] = (float)res;
    }
}

extern "C" void kernel_launch(void* const* d_in, const int* in_sizes, int n_in,
                              void* d_out, int out_size, void* d_ws, size_t ws_size,
                              hipStream_t stream) {
    const float* feats   = (const float*)d_in[0];
    const int*   classes = (const int*)d_in[1];
    float* out = (float*)d_out;

    int N = in_sizes[1];                       // 4096
    int D = in_sizes[0] / N;                   // 128
    int ntiles = N / 64;                       // 64
    int nblocks = ntiles * (ntiles + 1) / 2;   // 2080 blocks, one tile each

    // workspace layout: f16 scaled feats | u8 classes | u64 gH[NREP][NB2]
    _Float16* wsF = (_Float16*)d_ws;
    unsigned char* wsC = (unsigned char*)(wsF + (size_t)N * D);
    unsigned long long* gH = (unsigned long long*)(wsC + ((N + 15) & ~15));

    int ngroups = N * D / 8;                   // 65536 groups of 8 floats
    int cblocks = (ngroups + NTHREADS - 1) / NTHREADS;
    convert_kernel<<<cblocks, NTHREADS, 0, stream>>>(feats, classes, wsF, wsC,
                                                     gH, ngroups, N);
    hist_pairs_kernel<<<nblocks, NTHREADS, 0, stream>>>(wsF, wsC, gH, ntiles);
    finalize_kernel<<<1, NTHREADS, 0, stream>>>(gH, out);
}